// Round 1
// baseline (382.817 us; speedup 1.0000x reference)
//
#include <hip/hip_runtime.h>
#include <math.h>

#define PN 22536
#define BN 32
#define MN 16
#define CN 81
#define NMB ((PN + 255) / 256)   // 89 match blocks per image
#define NCB 2048                 // conf-kernel blocks

// Native base-2 transcendentals (v_exp_f32 / v_log_f32) with safe fallback.
#if __has_builtin(__builtin_amdgcn_exp2f)
#define EXP2(x) __builtin_amdgcn_exp2f(x)
#else
#define EXP2(x) exp2f(x)
#endif
#if __has_builtin(__builtin_amdgcn_logf)
#define LOG2(x) __builtin_amdgcn_logf(x)
#else
#define LOG2(x) log2f(x)
#endif

// ---------------------------------------------------------------------------
// Kernel 1: per-object best-prior argmax (prior_for_each_object).
// Packed key (iou_bits<<32 | ~p): max => first-occurrence argmax over p.
// ---------------------------------------------------------------------------
__global__ __launch_bounds__(256)
void pfo_kernel(const float* __restrict__ boxes,    // (B,M,4) xyxy
                const float* __restrict__ priors,   // (P,4) cxcy
                unsigned long long* __restrict__ pfo_key) // (B,M)
{
    const int b = blockIdx.y;
    const int p = blockIdx.x * 256 + threadIdx.x;

    __shared__ float4 sbox[MN];
    __shared__ float  sarea[MN];
    __shared__ unsigned long long skey[MN];
    if (threadIdx.x < MN) {
        float4 bx = reinterpret_cast<const float4*>(boxes)[b * MN + threadIdx.x];
        sbox[threadIdx.x]  = bx;
        sarea[threadIdx.x] = (bx.z - bx.x) * (bx.w - bx.y);
        skey[threadIdx.x]  = 0ull;
    }
    __syncthreads();

    float x0 = 0.f, y0 = 0.f, x1 = 0.f, y1 = 0.f, ab = 0.f;
    const bool valid = (p < PN);
    if (valid) {
        float4 pc = reinterpret_cast<const float4*>(priors)[p];
        float hw = pc.z / 2.0f, hh = pc.w / 2.0f;
        x0 = pc.x - hw; y0 = pc.y - hh;
        x1 = pc.x + hw; y1 = pc.y + hh;
        ab = (x1 - x0) * (y1 - y0);
    }

    const int lane = threadIdx.x & 63;
    #pragma unroll
    for (int m = 0; m < MN; ++m) {
        unsigned long long key = 0ull;
        if (valid) {
            float4 bx = sbox[m];
            float lx = fmaxf(bx.x, x0), ly = fmaxf(bx.y, y0);
            float rx = fminf(bx.z, x1), ry = fminf(bx.w, y1);
            float inter = fmaxf(rx - lx, 0.0f) * fmaxf(ry - ly, 0.0f);
            float iou = inter / (sarea[m] + ab - inter);
            key = ((unsigned long long)__float_as_uint(iou) << 32) |
                  (unsigned long long)(~(unsigned int)p);
        }
        #pragma unroll
        for (int off = 32; off >= 1; off >>= 1) {
            unsigned long long o = __shfl_down(key, (unsigned)off, 64);
            if (o > key) key = o;
        }
        if (lane == 0) atomicMax(&skey[m], key);
    }
    __syncthreads();
    if (threadIdx.x < MN)
        atomicMax(&pfo_key[b * MN + threadIdx.x], skey[threadIdx.x]);
}

// ---------------------------------------------------------------------------
// Kernel 2: thread-per-prior matching + DIoU + counts. Emits one byte/row:
// target label for focal loss (0..80) or 255 = skip (0.4 <= ofp < 0.5 band).
// Accumulates (loc_sum, pos_cnt, m_cnt) per block.
// ---------------------------------------------------------------------------
__global__ __launch_bounds__(256)
void match_kernel(const float* __restrict__ boxes,   // (B,M,4)
                  const int*   __restrict__ labels,  // (B,M)
                  const float* __restrict__ priors,  // (P,4) cxcy
                  const float* __restrict__ plocs,   // (B,P,4)
                  const unsigned long long* __restrict__ pfo_key,
                  unsigned char* __restrict__ labbyte,  // (B*P)
                  float4* __restrict__ mpart)           // (B*NMB)
{
    const int b = blockIdx.y;
    const int p = blockIdx.x * 256 + threadIdx.x;

    __shared__ float4 sbox[MN];
    __shared__ float  sarea[MN];
    __shared__ int    slab[MN];
    __shared__ int    spfo[MN];
    __shared__ float  sred[4][3];

    if (threadIdx.x < MN) {
        float4 bx = reinterpret_cast<const float4*>(boxes)[b * MN + threadIdx.x];
        sbox[threadIdx.x]  = bx;
        sarea[threadIdx.x] = (bx.z - bx.x) * (bx.w - bx.y);
        slab[threadIdx.x]  = labels[b * MN + threadIdx.x];
        spfo[threadIdx.x]  = (int)(~(unsigned int)(pfo_key[b * MN + threadIdx.x] &
                                                   0xFFFFFFFFull));
    }
    __syncthreads();

    float loc = 0.f, mc = 0.f, psc = 0.f;
    if (p < PN) {
        float4 pc = reinterpret_cast<const float4*>(priors)[p];
        float hw = pc.z / 2.0f, hh = pc.w / 2.0f;
        float qx0 = pc.x - hw, qy0 = pc.y - hh;
        float qx1 = pc.x + hw, qy1 = pc.y + hh;
        float ab  = (qx1 - qx0) * (qy1 - qy0);

        float best = -1.0f;
        int bestm = 0;
        #pragma unroll
        for (int m = 0; m < MN; ++m) {
            float4 bx = sbox[m];
            float lx = fmaxf(bx.x, qx0), ly = fmaxf(bx.y, qy0);
            float rx = fminf(bx.z, qx1), ry = fminf(bx.w, qy1);
            float inter = fmaxf(rx - lx, 0.0f) * fmaxf(ry - ly, 0.0f);
            float iou = inter / (sarea[m] + ab - inter);
            if (iou > best) { best = iou; bestm = m; }   // first-index wins
        }
        // pfo override: ascending m => last m wins for duplicate priors
        #pragma unroll
        for (int m = 0; m < MN; ++m)
            if (spfo[m] == p) { bestm = m; best = 1.0f; }

        bool pos = best >= 0.5f;
        bool neg = best < 0.4f;
        labbyte[(size_t)b * PN + p] =
            pos ? (unsigned char)slab[bestm] : (neg ? (unsigned char)0
                                                    : (unsigned char)255);
        if (pos || neg) mc = 1.0f;

        if (pos) {
            float4 g = reinterpret_cast<const float4*>(plocs)[(size_t)b * PN + p];
            float cx = g.x * pc.z / 10.0f + pc.x;
            float cy = g.y * pc.w / 10.0f + pc.y;
            float ww = expf(g.z / 5.0f) * pc.z;
            float hh2 = expf(g.w / 5.0f) * pc.w;
            float px0 = cx - ww / 2.0f, py0 = cy - hh2 / 2.0f;
            float px1 = cx + ww / 2.0f, py1 = cy + hh2 / 2.0f;

            float4 gb = sbox[bestm];
            float lx = fmaxf(px0, gb.x), ly = fmaxf(py0, gb.y);
            float rx = fminf(px1, gb.z), ry = fminf(py1, gb.w);
            float inter = fmaxf(rx - lx, 0.f) * fmaxf(ry - ly, 0.f);
            float apx = (px1 - px0) * (py1 - py0);
            float agx = (gb.z - gb.x) * (gb.w - gb.y);
            float iou = inter / (apx + agx - inter + 1e-7f);
            float cpx = (px0 + px1) / 2.0f, cpy = (py0 + py1) / 2.0f;
            float cgx = (gb.x + gb.z) / 2.0f, cgy = (gb.y + gb.w) / 2.0f;
            float dx = cpx - cgx, dy = cpy - cgy;
            float d2 = dx * dx + dy * dy;
            float ex0 = fminf(px0, gb.x), ey0 = fminf(py0, gb.y);
            float ex1 = fmaxf(px1, gb.z), ey1 = fmaxf(py1, gb.w);
            float ew = ex1 - ex0, eh = ey1 - ey0;
            float c2 = ew * ew + eh * eh + 1e-7f;
            loc = 1.0f - iou + d2 / c2;
            psc = 1.0f;
        }
    }

    #pragma unroll
    for (int off = 32; off >= 1; off >>= 1) {
        loc += __shfl_down(loc, (unsigned)off, 64);
        mc  += __shfl_down(mc,  (unsigned)off, 64);
        psc += __shfl_down(psc, (unsigned)off, 64);
    }
    const int lane = threadIdx.x & 63;
    const int w = threadIdx.x >> 6;
    if (lane == 0) { sred[w][0] = loc; sred[w][1] = mc; sred[w][2] = psc; }
    __syncthreads();
    if (threadIdx.x == 0) {
        float a = 0.f, bsum = 0.f, c = 0.f;
        #pragma unroll
        for (int i = 0; i < 4; ++i) {
            a += sred[i][0]; bsum += sred[i][1]; c += sred[i][2];
        }
        mpart[b * NMB + blockIdx.x] = make_float4(a, c, bsum, 0.f);
    }
}

// ---------------------------------------------------------------------------
// Kernel 3: focal confidence loss. 16 lanes per row, 4 rows per wave.
// Branchless body (no skip branch -> deep software pipelining of loads);
// base-2 softmax so all transcendentals are single native v_exp/v_log instrs.
// ---------------------------------------------------------------------------
__global__ __launch_bounds__(256)
void conf_kernel(const float* __restrict__ scores,       // (B,P,C)
                 const unsigned char* __restrict__ labbyte,
                 float* __restrict__ cpart)              // (gridDim.x)
{
    const int lane = threadIdx.x & 63;
    const int j    = lane & 15;
    const int g    = (lane >> 4);
    const int wave_g = (blockIdx.x * 256 + threadIdx.x) >> 6;
    const int stride = NCB * 16;     // rows per grid iteration
    const int R = BN * PN;           // divisible by 4

    const float LOG2E = 1.4426950408889634f;
    const float LN2   = 0.6931471805599453f;

    float conf = 0.f;

    // Each wave handles 4 consecutive rows (one per 16-lane group) per pass.
    for (int base = wave_g * 4; base < R; base += stride) {
        const int row = base + g;
        // one aligned 4-byte load covers all 4 groups' label bytes
        const unsigned int lb4 =
            *reinterpret_cast<const unsigned int*>(labbyte + base);
        const int lb  = (int)((lb4 >> (8 * g)) & 0xFFu);
        const int lbe = (lb == 255) ? 0 : lb;     // safe index for selection

        const float* srow = scores + (size_t)row * CN;
        // pre-scale into base-2 domain
        float s0 = srow[j]      * LOG2E;
        float s1 = srow[j + 16] * LOG2E;
        float s2 = srow[j + 32] * LOG2E;
        float s3 = srow[j + 48] * LOG2E;
        float s4 = srow[j + 64] * LOG2E;
        float s5 = (j == 0) ? srow[80] * LOG2E : -INFINITY;

        float mx = fmaxf(fmaxf(fmaxf(s0, s1), fmaxf(s2, s3)), fmaxf(s4, s5));
        #pragma unroll
        for (int off = 1; off < 16; off <<= 1)
            mx = fmaxf(mx, __shfl_xor(mx, off, 64));

        float es = EXP2(s0 - mx) + EXP2(s1 - mx) + EXP2(s2 - mx) +
                   EXP2(s3 - mx) + EXP2(s4 - mx) + EXP2(s5 - mx);
        #pragma unroll
        for (int off = 1; off < 16; off <<= 1)
            es += __shfl_xor(es, off, 64);

        // target (scaled) logit: class lbe lives in lane (lbe&15), slot (lbe>>4)
        int hi = lbe >> 4, lo = lbe & 15;
        float sel = s0;
        sel = (hi == 1) ? s1 : sel;
        sel = (hi == 2) ? s2 : sel;
        sel = (hi == 3) ? s3 : sel;
        sel = (hi == 4) ? s4 : sel;
        sel = (hi == 5) ? s5 : sel;
        float st = __shfl(sel, (lane & 48) | lo, 64);

        float q  = st - mx - LOG2(es);    // log2 p_t  (finite, <= 0)
        float pt = EXP2(q);
        float lp = q * LN2;               // natural-log p_t
        float om = 1.0f - pt;
        float w  = (lb != 255) ? 1.0f : 0.0f;
        if (j == 0) conf += w * 0.25f * om * om * (-lp);
    }

    #pragma unroll
    for (int off = 1; off < 64; off <<= 1)
        conf += __shfl_xor(conf, off, 64);

    __shared__ float sred[4];
    if (lane == 0) sred[threadIdx.x >> 6] = conf;
    __syncthreads();
    if (threadIdx.x == 0)
        cpart[blockIdx.x] = sred[0] + sred[1] + sred[2] + sred[3];
}

// ---------------------------------------------------------------------------
// Kernel 4: deterministic final reduction -> scalar loss
// ---------------------------------------------------------------------------
__global__ __launch_bounds__(256)
void reduce_kernel(const float4* __restrict__ mpart,   // (B*NMB): loc,pos,mcnt
                   const float*  __restrict__ cpart,   // (NCB)
                   float* __restrict__ out)
{
    const int NM = BN * NMB;
    float loc = 0.f, pcnt = 0.f, mcnt = 0.f, conf = 0.f;
    for (int i = threadIdx.x; i < NM; i += 256) {
        float4 v = mpart[i];
        loc += v.x; pcnt += v.y; mcnt += v.z;
    }
    for (int i = threadIdx.x; i < NCB; i += 256)
        conf += cpart[i];

    #pragma unroll
    for (int off = 1; off < 64; off <<= 1) {
        loc  += __shfl_xor(loc,  off, 64);
        pcnt += __shfl_xor(pcnt, off, 64);
        mcnt += __shfl_xor(mcnt, off, 64);
        conf += __shfl_xor(conf, off, 64);
    }
    __shared__ float s[4][4];
    int lane = threadIdx.x & 63, w = threadIdx.x >> 6;
    if (lane == 0) { s[w][0] = loc; s[w][1] = pcnt; s[w][2] = mcnt; s[w][3] = conf; }
    __syncthreads();
    if (threadIdx.x == 0) {
        float L = 0.f, Pc = 0.f, Mc = 0.f, Cf = 0.f;
        #pragma unroll
        for (int i = 0; i < 4; ++i) {
            L += s[i][0]; Pc += s[i][1]; Mc += s[i][2]; Cf += s[i][3];
        }
        out[0] = Cf / fmaxf(Mc, 1.0f) + L / fmaxf(Pc, 1.0f);
    }
}

// ---------------------------------------------------------------------------
extern "C" void kernel_launch(void* const* d_in, const int* in_sizes, int n_in,
                              void* d_out, int out_size, void* d_ws, size_t ws_size,
                              hipStream_t stream)
{
    const float* plocs  = (const float*)d_in[0];  // predicted_locs  (B,P,4)
    const float* scores = (const float*)d_in[1];  // predicted_scores(B,P,C)
    const float* boxes  = (const float*)d_in[2];  // boxes           (B,M,4)
    const int*   labels = (const int*)d_in[3];    // labels          (B,M)
    const float* priors = (const float*)d_in[4];  // priors_cxcy     (P,4)
    float* out = (float*)d_out;

    char* ws = (char*)d_ws;
    unsigned long long* pfo_key = (unsigned long long*)ws;        // 4096 B
    unsigned char* labbyte = (unsigned char*)(ws + 4096);         // B*P = 721152
    float4* mpart = (float4*)(ws + 4096 + 721152);                // 2848*16 B
    float*  cpart = (float*)(ws + 4096 + 721152 + BN * NMB * 16); // NCB*4 B

    hipMemsetAsync(pfo_key, 0, BN * MN * sizeof(unsigned long long), stream);

    dim3 gA(NMB, BN);
    pfo_kernel<<<gA, 256, 0, stream>>>(boxes, priors, pfo_key);
    match_kernel<<<gA, 256, 0, stream>>>(boxes, labels, priors, plocs,
                                         pfo_key, labbyte, mpart);
    conf_kernel<<<NCB, 256, 0, stream>>>(scores, labbyte, cpart);
    reduce_kernel<<<1, 256, 0, stream>>>(mpart, cpart, out);
}

// Round 2
// 356.930 us; speedup vs baseline: 1.0725x; 1.0725x over previous
//
#include <hip/hip_runtime.h>
#include <math.h>

#define PN 22536
#define BN 32
#define MN 16
#define CN 81
#define NMB ((PN + 255) / 256)   // 89 match blocks per image (PN = 88*256 + 8)

// Native base-2 transcendentals (v_exp_f32 / v_log_f32) with safe fallback.
#if __has_builtin(__builtin_amdgcn_exp2f)
#define EXP2(x) __builtin_amdgcn_exp2f(x)
#else
#define EXP2(x) exp2f(x)
#endif
#if __has_builtin(__builtin_amdgcn_logf)
#define LOG2(x) __builtin_amdgcn_logf(x)
#else
#define LOG2(x) log2f(x)
#endif

// ---------------------------------------------------------------------------
// Kernel 1: per-object best-prior argmax (prior_for_each_object).
// f32 max-reduce + ballot elects the wave winner (first lane = smallest p);
// cross-wave/block combine keeps the exact packed u64 key (iou_bits<<32 | ~p).
// ---------------------------------------------------------------------------
__global__ __launch_bounds__(256)
void pfo_kernel(const float* __restrict__ boxes,    // (B,M,4) xyxy
                const float* __restrict__ priors,   // (P,4) cxcy
                unsigned long long* __restrict__ pfo_key) // (B,M)
{
    const int b = blockIdx.y;
    const int p = blockIdx.x * 256 + threadIdx.x;

    __shared__ float4 sbox[MN];
    __shared__ float  sarea[MN];
    __shared__ unsigned long long skey[MN];
    if (threadIdx.x < MN) {
        float4 bx = reinterpret_cast<const float4*>(boxes)[b * MN + threadIdx.x];
        sbox[threadIdx.x]  = bx;
        sarea[threadIdx.x] = (bx.z - bx.x) * (bx.w - bx.y);
        skey[threadIdx.x]  = 0ull;
    }
    __syncthreads();

    float x0 = 0.f, y0 = 0.f, x1 = 0.f, y1 = 0.f, ab = 0.f;
    const bool valid = (p < PN);
    if (valid) {
        float4 pc = reinterpret_cast<const float4*>(priors)[p];
        float hw = pc.z / 2.0f, hh = pc.w / 2.0f;
        x0 = pc.x - hw; y0 = pc.y - hh;
        x1 = pc.x + hw; y1 = pc.y + hh;
        ab = (x1 - x0) * (y1 - y0);
    }

    const int lane = threadIdx.x & 63;
    #pragma unroll
    for (int m = 0; m < MN; ++m) {
        float iou = -INFINITY;
        if (valid) {
            float4 bx = sbox[m];
            float lx = fmaxf(bx.x, x0), ly = fmaxf(bx.y, y0);
            float rx = fminf(bx.z, x1), ry = fminf(bx.w, y1);
            float inter = fmaxf(rx - lx, 0.0f) * fmaxf(ry - ly, 0.0f);
            iou = inter / (sarea[m] + ab - inter);      // >= 0 for valid lanes
        }
        float mx = iou;
        #pragma unroll
        for (int off = 1; off < 64; off <<= 1)
            mx = fmaxf(mx, __shfl_xor(mx, off, 64));
        unsigned long long mask = __ballot(iou == mx);
        int lane0 = (int)__ffsll((unsigned long long)mask) - 1;
        if (valid && lane == lane0) {
            unsigned long long key =
                ((unsigned long long)__float_as_uint(iou) << 32) |
                (unsigned long long)(~(unsigned int)p);
            atomicMax(&skey[m], key);
        }
    }
    __syncthreads();
    if (threadIdx.x < MN)
        atomicMax(&pfo_key[b * MN + threadIdx.x], skey[threadIdx.x]);
}

// ---------------------------------------------------------------------------
// Kernel 2 (fused match + focal conf):
// Phase A: thread-per-prior matching + DIoU; label byte kept in LDS.
// Phase B: focal loss for this block's 256 rows. Each wave handles 8-row
//   packs (8*81 floats = 162 float4, 16B-aligned since PN%8==0): global
//   float4 stream -> LDS (wave-coherent, no barrier) -> 8-lane row groups.
// Emits per-block float4 (loc_sum, pos_cnt, m_cnt, conf_sum).
// ---------------------------------------------------------------------------
__global__ __launch_bounds__(256)
void match_conf_kernel(const float* __restrict__ boxes,   // (B,M,4)
                       const int*   __restrict__ labels,  // (B,M)
                       const float* __restrict__ priors,  // (P,4) cxcy
                       const float* __restrict__ plocs,   // (B,P,4)
                       const float* __restrict__ scores,  // (B,P,C)
                       const unsigned long long* __restrict__ pfo_key,
                       float4* __restrict__ mpart)        // (B*NMB)
{
    const int b  = blockIdx.y;
    const int p0 = blockIdx.x * 256;
    const int p  = p0 + threadIdx.x;

    __shared__ float4 sbox[MN];
    __shared__ float  sarea[MN];
    __shared__ int    slab[MN];
    __shared__ int    spfo[MN];
    __shared__ unsigned char slb[256];
    __shared__ float4 spack4[4][162];     // per-wave 8-row score pack
    __shared__ float  sred[4][4];

    if (threadIdx.x < MN) {
        float4 bx = reinterpret_cast<const float4*>(boxes)[b * MN + threadIdx.x];
        sbox[threadIdx.x]  = bx;
        sarea[threadIdx.x] = (bx.z - bx.x) * (bx.w - bx.y);
        slab[threadIdx.x]  = labels[b * MN + threadIdx.x];
        spfo[threadIdx.x]  = (int)(~(unsigned int)(pfo_key[b * MN + threadIdx.x] &
                                                   0xFFFFFFFFull));
    }
    __syncthreads();

    // ---------------- phase A: matching ----------------
    float loc = 0.f, mc = 0.f, psc = 0.f;
    unsigned char myl = 255;
    if (p < PN) {
        float4 pc = reinterpret_cast<const float4*>(priors)[p];
        float hw = pc.z / 2.0f, hh = pc.w / 2.0f;
        float qx0 = pc.x - hw, qy0 = pc.y - hh;
        float qx1 = pc.x + hw, qy1 = pc.y + hh;
        float ab  = (qx1 - qx0) * (qy1 - qy0);

        float best = -1.0f;
        int bestm = 0;
        #pragma unroll
        for (int m = 0; m < MN; ++m) {
            float4 bx = sbox[m];
            float lx = fmaxf(bx.x, qx0), ly = fmaxf(bx.y, qy0);
            float rx = fminf(bx.z, qx1), ry = fminf(bx.w, qy1);
            float inter = fmaxf(rx - lx, 0.0f) * fmaxf(ry - ly, 0.0f);
            float iou = inter / (sarea[m] + ab - inter);
            if (iou > best) { best = iou; bestm = m; }   // first-index wins
        }
        // pfo override: ascending m => last m wins for duplicate priors
        #pragma unroll
        for (int m = 0; m < MN; ++m)
            if (spfo[m] == p) { bestm = m; best = 1.0f; }

        bool pos = best >= 0.5f;
        bool neg = best < 0.4f;
        myl = pos ? (unsigned char)slab[bestm]
                  : (neg ? (unsigned char)0 : (unsigned char)255);
        if (pos || neg) mc = 1.0f;

        if (pos) {
            float4 g = reinterpret_cast<const float4*>(plocs)[(size_t)b * PN + p];
            float cx = g.x * pc.z / 10.0f + pc.x;
            float cy = g.y * pc.w / 10.0f + pc.y;
            float ww = expf(g.z / 5.0f) * pc.z;
            float hh2 = expf(g.w / 5.0f) * pc.w;
            float px0 = cx - ww / 2.0f, py0 = cy - hh2 / 2.0f;
            float px1 = cx + ww / 2.0f, py1 = cy + hh2 / 2.0f;

            float4 gb = sbox[bestm];
            float lx = fmaxf(px0, gb.x), ly = fmaxf(py0, gb.y);
            float rx = fminf(px1, gb.z), ry = fminf(py1, gb.w);
            float inter = fmaxf(rx - lx, 0.f) * fmaxf(ry - ly, 0.f);
            float apx = (px1 - px0) * (py1 - py0);
            float agx = (gb.z - gb.x) * (gb.w - gb.y);
            float iou = inter / (apx + agx - inter + 1e-7f);
            float cpx = (px0 + px1) / 2.0f, cpy = (py0 + py1) / 2.0f;
            float cgx = (gb.x + gb.z) / 2.0f, cgy = (gb.y + gb.w) / 2.0f;
            float dx = cpx - cgx, dy = cpy - cgy;
            float d2 = dx * dx + dy * dy;
            float ex0 = fminf(px0, gb.x), ey0 = fminf(py0, gb.y);
            float ex1 = fmaxf(px1, gb.z), ey1 = fmaxf(py1, gb.w);
            float ew = ex1 - ex0, eh = ey1 - ey0;
            float c2 = ew * ew + eh * eh + 1e-7f;
            loc = 1.0f - iou + d2 / c2;
            psc = 1.0f;
        }
    }
    slb[threadIdx.x] = myl;

    #pragma unroll
    for (int off = 32; off >= 1; off >>= 1) {
        loc += __shfl_down(loc, (unsigned)off, 64);
        mc  += __shfl_down(mc,  (unsigned)off, 64);
        psc += __shfl_down(psc, (unsigned)off, 64);
    }
    const int lane = threadIdx.x & 63;
    const int w    = threadIdx.x >> 6;
    if (lane == 0) { sred[w][0] = loc; sred[w][1] = mc; sred[w][2] = psc; }
    __syncthreads();   // slb + sred visible to all waves

    // ---------------- phase B: focal conf ----------------
    const int g8 = lane >> 3;          // row within pack (0..7)
    const int j  = lane & 7;           // 8 lanes per row
    const float LOG2E = 1.4426950408889634f;
    const float LN2   = 0.6931471805599453f;

    float confs = 0.f;
    for (int it = 0; it < 8; ++it) {
        const int prow = w * 64 + it * 8;      // block-local pack start row
        const int gp   = p0 + prow;            // prior index of pack start
        if (gp < PN) {                         // PN%8==0 -> pack fully valid
            const size_t fbase = ((size_t)b * PN + gp) * (size_t)CN;
            const float4* gsrc = reinterpret_cast<const float4*>(scores + fbase);
            float4* dst = spack4[w];
            dst[lane]      = gsrc[lane];
            dst[lane + 64] = gsrc[lane + 64];
            if (lane < 34) dst[lane + 128] = gsrc[lane + 128];
            // wave-coherent LDS: no barrier needed (compiler inserts waitcnt)
            const float* rowp =
                reinterpret_cast<const float*>(spack4[w]) + g8 * 81;

            float v[10];
            #pragma unroll
            for (int k = 0; k < 10; ++k) v[k] = rowp[j + 8 * k];
            float v80 = (j == 0) ? rowp[80] : -INFINITY;

            float mx = v80;
            #pragma unroll
            for (int k = 0; k < 10; ++k) mx = fmaxf(mx, v[k]);
            #pragma unroll
            for (int off = 1; off < 8; off <<= 1)
                mx = fmaxf(mx, __shfl_xor(mx, off, 64));

            const float mx2 = mx * LOG2E;
            float es = EXP2(fmaf(v80, LOG2E, -mx2));   // exp2(-inf)=0 for j!=0
            #pragma unroll
            for (int k = 0; k < 10; ++k)
                es += EXP2(fmaf(v[k], LOG2E, -mx2));
            #pragma unroll
            for (int off = 1; off < 8; off <<= 1)
                es += __shfl_xor(es, off, 64);

            const int lb  = slb[prow + g8];
            const int lbe = (lb == 255) ? 0 : lb;
            const float st = rowp[lbe];                // group-uniform broadcast
            float q  = fmaf(st, LOG2E, -mx2) - LOG2(es);  // log2 p_t
            float pt = EXP2(q);
            float om = 1.0f - pt;
            float fl = 0.25f * om * om * (-(q * LN2));
            if (j == 0 && lb != 255) confs += fl;
        }
    }

    #pragma unroll
    for (int off = 1; off < 64; off <<= 1)
        confs += __shfl_xor(confs, off, 64);
    if (lane == 0) sred[w][3] = confs;
    __syncthreads();

    if (threadIdx.x == 0) {
        float a = 0.f, bsum = 0.f, c = 0.f, cf = 0.f;
        #pragma unroll
        for (int i = 0; i < 4; ++i) {
            a += sred[i][0]; bsum += sred[i][1]; c += sred[i][2]; cf += sred[i][3];
        }
        mpart[b * NMB + blockIdx.x] = make_float4(a, c, bsum, cf);
    }
}

// ---------------------------------------------------------------------------
// Kernel 3: deterministic final reduction -> scalar loss
// ---------------------------------------------------------------------------
__global__ __launch_bounds__(256)
void reduce_kernel(const float4* __restrict__ mpart,   // (B*NMB): loc,pos,mcnt,conf
                   float* __restrict__ out)
{
    const int NM = BN * NMB;
    float loc = 0.f, pcnt = 0.f, mcnt = 0.f, conf = 0.f;
    for (int i = threadIdx.x; i < NM; i += 256) {
        float4 v = mpart[i];
        loc += v.x; pcnt += v.y; mcnt += v.z; conf += v.w;
    }

    #pragma unroll
    for (int off = 1; off < 64; off <<= 1) {
        loc  += __shfl_xor(loc,  off, 64);
        pcnt += __shfl_xor(pcnt, off, 64);
        mcnt += __shfl_xor(mcnt, off, 64);
        conf += __shfl_xor(conf, off, 64);
    }
    __shared__ float s[4][4];
    int lane = threadIdx.x & 63, w = threadIdx.x >> 6;
    if (lane == 0) { s[w][0] = loc; s[w][1] = pcnt; s[w][2] = mcnt; s[w][3] = conf; }
    __syncthreads();
    if (threadIdx.x == 0) {
        float L = 0.f, Pc = 0.f, Mc = 0.f, Cf = 0.f;
        #pragma unroll
        for (int i = 0; i < 4; ++i) {
            L += s[i][0]; Pc += s[i][1]; Mc += s[i][2]; Cf += s[i][3];
        }
        out[0] = Cf / fmaxf(Mc, 1.0f) + L / fmaxf(Pc, 1.0f);
    }
}

// ---------------------------------------------------------------------------
extern "C" void kernel_launch(void* const* d_in, const int* in_sizes, int n_in,
                              void* d_out, int out_size, void* d_ws, size_t ws_size,
                              hipStream_t stream)
{
    const float* plocs  = (const float*)d_in[0];  // predicted_locs  (B,P,4)
    const float* scores = (const float*)d_in[1];  // predicted_scores(B,P,C)
    const float* boxes  = (const float*)d_in[2];  // boxes           (B,M,4)
    const int*   labels = (const int*)d_in[3];    // labels          (B,M)
    const float* priors = (const float*)d_in[4];  // priors_cxcy     (P,4)
    float* out = (float*)d_out;

    char* ws = (char*)d_ws;
    unsigned long long* pfo_key = (unsigned long long*)ws;   // 4096 B
    float4* mpart = (float4*)(ws + 4096);                    // 2848*16 B

    hipMemsetAsync(pfo_key, 0, BN * MN * sizeof(unsigned long long), stream);

    dim3 gA(NMB, BN);
    pfo_kernel<<<gA, 256, 0, stream>>>(boxes, priors, pfo_key);
    match_conf_kernel<<<gA, 256, 0, stream>>>(boxes, labels, priors, plocs,
                                              scores, pfo_key, mpart);
    reduce_kernel<<<1, 256, 0, stream>>>(mpart, out);
}